// Round 2
// baseline (169.781 us; speedup 1.0000x reference)
//
#include <hip/hip_runtime.h>
#include <hip/hip_bf16.h>

// SDF volume rendering (NeuS/VolSDF-style), float32 in/out, per reference.
//
// Per ray (96 samples):
//   alpha_i = 1 - exp(-beta * sigmoid(-sdf_i * beta))
//   t_i     = 1 - alpha_i + 1e-10 = exp(-beta * sigmoid(-sdf_i*beta)) + 1e-10
//   trans_i = prod_{j<i} t_j          (exclusive cumprod)
//   w_i     = alpha_i * trans_i
//   depth   = sum w_i * z_i ;  rgb_c = sum w_i * rgb_{i,c}
//
// Layout: 32 lanes per ray (2 rays per wave64). 3 rounds of 32 samples.
// Exclusive cumprod = per-round 32-lane inclusive shuffle-scan + scalar carry.
// sdf/z_vals passthrough outputs are copied in-loop from the already-loaded
// values (bit-exact f32 copy), avoiding a second read pass.

#define SDFR_N_SAMPLES 96

__global__ __launch_bounds__(256) void sdf_render_kernel(
    const float*  __restrict__ rgb,     // [N, 96, 3] f32
    const float*  __restrict__ sdf,     // [N, 96]    f32
    const float*  __restrict__ zv,      // [N, 96]    f32
    const int*    __restrict__ beta_p,  // scalar (int32, or f32 bit pattern)
    float* __restrict__ out_depth,      // [N]
    float* __restrict__ out_rgb,        // [N, 3]
    float* __restrict__ out_sdf,        // [N, 96]
    float* __restrict__ out_z,          // [N, 96]
    int n_rays)
{
    // Defensive beta decode: a small int (e.g. 10) is the value itself; a
    // huge magnitude is almost certainly an f32 bit pattern (10.0f=0x41200000).
    int bi = *beta_p;
    float beta;
    if (bi > 1000000 || bi < -1000000) {
        union { int i; float f; } c; c.i = bi; beta = c.f;
    } else {
        beta = (float)bi;
    }

    const int lane = threadIdx.x & 63;
    const int half = lane >> 5;        // which ray within the wave
    const int l    = lane & 31;        // lane within the 32-lane ray group
    const int wave = threadIdx.x >> 6; // wave within block (0..3)
    const int ray  = (blockIdx.x * 4 + wave) * 2 + half;
    if (ray >= n_rays) return;
    const int base = ray * SDFR_N_SAMPLES;

    float carry = 1.0f;                 // product of all t from prior rounds
    float depth = 0.0f, r0 = 0.0f, r1 = 0.0f, r2 = 0.0f;

    #pragma unroll
    for (int k = 0; k < 3; ++k) {
        const int idx = base + 32 * k + l;   // coalesced 128B segment
        const float sdf_f = sdf[idx];
        const float z_f   = zv[idx];
        out_sdf[idx] = sdf_f;                // bit-exact passthrough
        out_z[idx]   = z_f;

        const float x   = -sdf_f * beta;
        const float sig = 1.0f / (1.0f + __expf(-x));
        const float e   = __expf(-beta * sig);
        const float alpha = 1.0f - e;
        const float t     = e + 1e-10f;      // == 1 - alpha + 1e-10

        // inclusive prefix-product scan across the 32-lane segment
        float scan = t;
        #pragma unroll
        for (int d = 1; d < 32; d <<= 1) {
            float v = __shfl_up(scan, d, 32);
            if (l >= d) scan *= v;
        }
        const float excl = __shfl_up(scan, 1, 32);        // inclusive at l-1
        const float P = carry * ((l == 0) ? 1.0f : excl); // exclusive cumprod
        const float w = alpha * P;

        depth += w * z_f;
        const float3 c = *(const float3*)(rgb + (size_t)idx * 3);
        r0 += w * c.x;
        r1 += w * c.y;
        r2 += w * c.z;

        carry *= __shfl(scan, 31, 32);   // total product of this round
    }

    // reduce the 4 accumulators across the 32-lane segment
    #pragma unroll
    for (int d = 16; d >= 1; d >>= 1) {
        depth += __shfl_xor(depth, d, 32);
        r0    += __shfl_xor(r0, d, 32);
        r1    += __shfl_xor(r1, d, 32);
        r2    += __shfl_xor(r2, d, 32);
    }

    if (l == 0) {
        out_depth[ray]       = depth;
        out_rgb[ray * 3 + 0] = r0;
        out_rgb[ray * 3 + 1] = r1;
        out_rgb[ray * 3 + 2] = r2;
    }
}

extern "C" void kernel_launch(void* const* d_in, const int* in_sizes, int n_in,
                              void* d_out, int out_size, void* d_ws, size_t ws_size,
                              hipStream_t stream) {
    (void)n_in; (void)d_ws; (void)ws_size; (void)out_size;

    const float* rgb    = (const float*)d_in[0];
    const float* sdf    = (const float*)d_in[1];
    const float* zv     = (const float*)d_in[2];
    const int*   beta_p = (const int*)d_in[3];

    const int n_rays = in_sizes[1] / SDFR_N_SAMPLES;  // 65536

    // output layout (f32 elements): depth[N] | rgb[N*3] | sdf[N*96] | z[N*96]
    float* out_depth = (float*)d_out;
    float* out_rgb   = out_depth + n_rays;
    float* out_sdf   = out_rgb   + (size_t)n_rays * 3;
    float* out_z     = out_sdf   + (size_t)n_rays * SDFR_N_SAMPLES;

    // 2 rays per wave64, 4 waves per block -> 8 rays/block
    const int rays_per_block = 8;
    const int grid = (n_rays + rays_per_block - 1) / rays_per_block;
    sdf_render_kernel<<<grid, 256, 0, stream>>>(
        rgb, sdf, zv, beta_p, out_depth, out_rgb, out_sdf, out_z, n_rays);
}